// Round 15
// baseline (88.826 us; speedup 1.0000x reference)
//
#include <hip/hip_runtime.h>
#include <hip/hip_bf16.h>
#include <math.h>

#define N_NODES 50000
#define N_EDGES 800000
#define DIM 96
#define HEADS 4
#define HEAD_DIM 24
#define SLOPE 0.2f
#define LN_EPS 1e-5f

#define CH 2048                                    // edges per sort chunk
#define NCH ((N_EDGES + CH - 1) / CH)              // 391
#define NB2 ((N_NODES + 255) / 256)                // 196 coarse buckets (dst>>8)

#define NGRP (N_NODES / 16)                        // 3125 (exact)
#define GRID_MM 784                                // 3136 waves >= 3125
#define HLP 100                                    // hl row pad (f32)

typedef __attribute__((ext_vector_type(8))) short bf16x8;
typedef __attribute__((ext_vector_type(4))) float f32x4;

__device__ __forceinline__ unsigned short f2bf(float f) {
    unsigned u = __float_as_uint(f);
    u += 0x7FFFu + ((u >> 16) & 1u);          // round-to-nearest-even
    return (unsigned short)(u >> 16);
}
__device__ __forceinline__ float bf2f(unsigned short v) {
    return __uint_as_float(((unsigned)v) << 16);
}
__device__ __forceinline__ unsigned pack2bf(float a, float b) {
    return (unsigned)f2bf(a) | ((unsigned)f2bf(b) << 16);
}

// ---------------------------------------------------------------------------
// Sort pass A (+fused prep): blocks 0-8 also build bf16 B-fragments for
// W and PW^T. Then per-chunk LDS histogram over 196 coarse buckets.
// ---------------------------------------------------------------------------
__global__ __launch_bounds__(256) void k_sortA(
    const int* __restrict__ ei, int* __restrict__ cnt,
    const float* __restrict__ W, const float* __restrict__ PW,
    unsigned short* __restrict__ wfr, unsigned short* __restrict__ pwfr)
{
    const int gi = blockIdx.x * 256 + threadIdx.x;
    if (gi < 2 * 18 * 64) {                       // fused k_prep
        const int a = gi / (18 * 64);
        const int rem = gi % (18 * 64);
        const int frag = rem / 64, lane = rem % 64;
        const int fb = frag / 3, kc = frag % 3;
        const int m = lane & 15, g = lane >> 4;
        unsigned short* dst = (a ? pwfr : wfr) + (size_t)(frag * 64 + lane) * 8;
        #pragma unroll
        for (int j = 0; j < 8; ++j) {
            const int k = kc * 32 + g * 8 + j, f = fb * 16 + m;
            const float v = a ? PW[f * DIM + k] : W[k * DIM + f];   // B[k][f]
            dst[j] = f2bf(v);
        }
    }
    __shared__ int h[NB2];
    const int b = blockIdx.x, t = threadIdx.x;
    for (int k = t; k < NB2; k += 256) h[k] = 0;
    __syncthreads();
    const int e0 = b * CH;
    const int e1 = (e0 + CH < N_EDGES) ? e0 + CH : N_EDGES;
    for (int e = e0 + t; e < e1; e += 256) {
        const int d = ei[N_EDGES + e];
        if ((unsigned)d < N_NODES) atomicAdd(&h[d >> 8], 1);
    }
    __syncthreads();
    for (int k = t; k < NB2; k += 256) cnt[k * NCH + b] = h[k];
}

__global__ __launch_bounds__(512) void k_sortB1(const int* __restrict__ cnt,
                                                int* __restrict__ colpre,
                                                int* __restrict__ colsum)
{
    __shared__ int s[512];
    const int k = blockIdx.x, t = threadIdx.x;
    const int v = (t < NCH) ? cnt[k * NCH + t] : 0;
    s[t] = v;
    __syncthreads();
    #pragma unroll
    for (int off = 1; off < 512; off <<= 1) {
        const int u = (t >= off) ? s[t - off] : 0;
        __syncthreads();
        s[t] += u;
        __syncthreads();
    }
    if (t < NCH) colpre[k * NCH + t] = s[t] - v;
    if (t == 511) colsum[k] = s[511];
}

// ---------------------------------------------------------------------------
// Sort pass C: place packed (s | d_local<<16) into coarse-bucket order.
// bbase derived from a local LDS scan of colsum (k_sortB2 eliminated).
// ---------------------------------------------------------------------------
__global__ __launch_bounds__(256) void k_sortC(const int* __restrict__ ei,
                                               const int* __restrict__ colpre,
                                               const int* __restrict__ colsum,
                                               unsigned* __restrict__ staged)
{
    __shared__ int bs[256];
    __shared__ int lcur[NB2];
    const int b = blockIdx.x, t = threadIdx.x;
    const int v = (t < NB2) ? colsum[t] : 0;
    bs[t] = v;
    __syncthreads();
    #pragma unroll
    for (int off = 1; off < 256; off <<= 1) {       // inclusive scan of colsum
        const int u = (t >= off) ? bs[t - off] : 0;
        __syncthreads();
        bs[t] += u;
        __syncthreads();
    }
    if (t < NB2) lcur[t] = (bs[t] - v) + colpre[t * NCH + b];
    __syncthreads();
    const int e0 = b * CH;
    const int e1 = (e0 + CH < N_EDGES) ? e0 + CH : N_EDGES;
    for (int e = e0 + t; e < e1; e += 256) {
        int s = ei[e];
        const int d = ei[N_EDGES + e];
        if ((unsigned)d >= N_NODES) continue;
        if ((unsigned)s >= N_NODES) s = d;
        const int pos = atomicAdd(&lcur[d >> 8], 1);
        staged[pos] = (unsigned)s | ((unsigned)(d & 255) << 16);
    }
}

__global__ __launch_bounds__(512) void k_sortD(
    const unsigned* __restrict__ staged, const int* __restrict__ colsum,
    int* __restrict__ offsets, int* __restrict__ ssrc)
{
    __shared__ int bs[256];
    __shared__ int hist[256];
    __shared__ int sc[256];
    __shared__ int rs_s, re_s, tot_s;
    const int k = blockIdx.x, t = threadIdx.x;
    if (t < 256) {                                  // local scan -> bbase[k], [k+1]
        const int v = (t < NB2) ? colsum[t] : 0;
        bs[t] = v;
        __syncthreads();
        #pragma unroll
        for (int off = 1; off < 256; off <<= 1) {
            const int u = (t >= off) ? bs[t - off] : 0;
            __syncthreads();
            bs[t] += u;
            __syncthreads();
        }
        if (t == k) { rs_s = bs[t] - v; re_s = bs[t]; }
        if (t == NB2 - 1) tot_s = bs[t];
    } else {
        __syncthreads();
        #pragma unroll
        for (int off = 1; off < 256; off <<= 1) { __syncthreads(); __syncthreads(); }
    }
    __syncthreads();
    const int first = k << 8;
    const int nn = (first + 256 < N_NODES) ? 256 : N_NODES - first;
    const int rs = rs_s, re = re_s;
    if (t < 256) hist[t] = 0;
    __syncthreads();
    for (int i = rs + t; i < re; i += 512)
        atomicAdd(&hist[staged[i] >> 16], 1);
    __syncthreads();
    if (t < 256) sc[t] = hist[t];
    __syncthreads();
    #pragma unroll
    for (int off = 1; off < 256; off <<= 1) {
        int u = 0;
        if (t < 256 && t >= off) u = sc[t - off];
        __syncthreads();
        if (t < 256) sc[t] += u;
        __syncthreads();
    }
    int mycur = 0;
    if (t < 256) {
        mycur = rs + sc[t] - hist[t];
        if (t < nn) offsets[first + t] = mycur;
    }
    if (k == 0 && t == 0) offsets[N_NODES] = tot_s;
    __syncthreads();
    if (t < 256) hist[t] = mycur;
    __syncthreads();
    for (int i = rs + t; i < re; i += 512) {
        const unsigned pk = staged[i];
        const int pos = atomicAdd(&hist[pk >> 16], 1);
        ssrc[pos] = (int)(pk & 0xffffu);
    }
}

// ---------------------------------------------------------------------------
// Kernel A (MFMA): h = x @ W. One wave per 16-node group; 18 B-frags in VGPR.
// ---------------------------------------------------------------------------
__global__ __launch_bounds__(256) void k_transform(
    const float* __restrict__ x, const unsigned short* __restrict__ wfr,
    const float* __restrict__ attS, const float* __restrict__ attD,
    unsigned short* __restrict__ hb, float* __restrict__ asrc,
    float* __restrict__ adst)
{
    __shared__ float hl[4][16][HLP];          // per-wave slices, 25.6 KB
    const int tid = threadIdx.x, wv = tid >> 6, l = tid & 63;
    const int m = l & 15, g = l >> 4;

    bf16x8 wf[6][3];
    #pragma unroll
    for (int fb = 0; fb < 6; ++fb)
        #pragma unroll
        for (int kc = 0; kc < 3; ++kc)
            wf[fb][kc] = *(const bf16x8*)&wfr[(size_t)((fb * 3 + kc) * 64 + l) * 8];

    float (*h)[HLP] = hl[wv];

    for (int grp = blockIdx.x * 4 + wv; grp < NGRP; grp += gridDim.x * 4) {
        const int n0 = grp * 16;
        f32x4 acc[6];
        #pragma unroll
        for (int fb = 0; fb < 6; ++fb)
            #pragma unroll
            for (int e = 0; e < 4; ++e) acc[fb][e] = 0.f;

        #pragma unroll
        for (int kc = 0; kc < 3; ++kc) {
            const float* xp = x + (size_t)(n0 + m) * DIM + kc * 32 + g * 8;
            const float4 xa = *(const float4*)xp;
            const float4 xb = *(const float4*)(xp + 4);
            uint4 au;
            au.x = pack2bf(xa.x, xa.y); au.y = pack2bf(xa.z, xa.w);
            au.z = pack2bf(xb.x, xb.y); au.w = pack2bf(xb.z, xb.w);
            const bf16x8 af = *(const bf16x8*)&au;
            #pragma unroll
            for (int fb = 0; fb < 6; ++fb)
                acc[fb] = __builtin_amdgcn_mfma_f32_16x16x32_bf16(af, wf[fb][kc], acc[fb], 0, 0, 0);
        }
        #pragma unroll
        for (int fb = 0; fb < 6; ++fb)
            #pragma unroll
            for (int r = 0; r < 4; ++r)
                h[g * 4 + r][fb * 16 + m] = acc[fb][r];

        {   // attention dots: lane -> (node = l>>2, head = l&3)
            const int nd = l >> 2, hd = l & 3;
            const float* hr = &h[nd][hd * HEAD_DIM];
            const float* as_ = attS + hd * HEAD_DIM;
            const float* ad_ = attD + hd * HEAD_DIM;
            float s = 0.f, dd = 0.f;
            #pragma unroll
            for (int kk = 0; kk < HEAD_DIM; ++kk) {
                const float hv = hr[kk];
                s += hv * as_[kk];
                dd += hv * ad_[kk];
            }
            asrc[n0 * HEADS + l] = s;
            adst[n0 * HEADS + l] = dd;
        }
        #pragma unroll
        for (int c = l; c < 192; c += 64) {
            const int n = c / 12, q = c % 12;
            const float4 lo = *(const float4*)&h[n][q * 8];
            const float4 hi = *(const float4*)&h[n][q * 8 + 4];
            uint4 hv;
            hv.x = pack2bf(lo.x, lo.y); hv.y = pack2bf(lo.z, lo.w);
            hv.z = pack2bf(hi.x, hi.y); hv.w = pack2bf(hi.z, hi.w);
            *(uint4*)&hb[(size_t)(n0 + n) * DIM + q * 8] = hv;
        }
    }
}

// ---------------------------------------------------------------------------
// Kernel C: gather-aggregate, TWO consecutive nodes per wave (CSR ranges
// adjacent). Both sv preloads + both batch-weight phases issued up front;
// node B's pipeline fill issued before node A's drain. 8-deep pipelines.
// ---------------------------------------------------------------------------
__global__ __launch_bounds__(256) void k_aggregate(
    const int* __restrict__ offsets, const int* __restrict__ ssrc,
    const unsigned short* __restrict__ hb, const float* __restrict__ asrc,
    const float* __restrict__ adst, const float* __restrict__ gb,
    unsigned short* __restrict__ gbuf)
{
    __shared__ float wlds[4][512];               // per-wave: 128 edges x 4 heads
    const int wid  = (blockIdx.x * 256 + threadIdx.x) >> 6;
    const int lane = threadIdx.x & 63;
    const int d0 = wid * 2;                      // N_NODES even -> d0+1 valid
    if (d0 >= N_NODES) return;
    const int d1 = d0 + 1;
    const int wv = (threadIdx.x >> 6) & 3;
    const int lp = (lane < 48) ? lane : 47;
    const int f0 = lp * 2;
    const int hd = f0 / HEAD_DIM;

    const int rs0 = offsets[d0], re0 = offsets[d1], re1 = offsets[d0 + 2];
    const int deg0 = re0 - rs0, deg1 = re1 - re0;

    const int sv0 = (lane < deg0) ? ssrc[rs0 + lane] : d0;   // coalesced
    const int sv1 = (lane < deg1) ? ssrc[re0 + lane] : d1;

    {   // batch weights for both nodes (independent gathers)
        const float4 as0 = *(const float4*)&asrc[sv0 * 4];
        const float4 ad0 = *(const float4*)&adst[d0 * 4];
        const float4 as1 = *(const float4*)&asrc[sv1 * 4];
        const float4 ad1 = *(const float4*)&adst[d1 * 4];
        float l; float4 w;
        l = as0.x + ad0.x; l = (l > 0.f) ? l : SLOPE * l; w.x = __expf(l);
        l = as0.y + ad0.y; l = (l > 0.f) ? l : SLOPE * l; w.y = __expf(l);
        l = as0.z + ad0.z; l = (l > 0.f) ? l : SLOPE * l; w.z = __expf(l);
        l = as0.w + ad0.w; l = (l > 0.f) ? l : SLOPE * l; w.w = __expf(l);
        *(float4*)&wlds[wv][lane * 4] = w;
        l = as1.x + ad1.x; l = (l > 0.f) ? l : SLOPE * l; w.x = __expf(l);
        l = as1.y + ad1.y; l = (l > 0.f) ? l : SLOPE * l; w.y = __expf(l);
        l = as1.z + ad1.z; l = (l > 0.f) ? l : SLOPE * l; w.z = __expf(l);
        l = as1.w + ad1.w; l = (l > 0.f) ? l : SLOPE * l; w.w = __expf(l);
        *(float4*)&wlds[wv][(64 + lane) * 4] = w;   // wave-synchronous
    }

    float a00, a01, ds0, a10, a11, ds1;
    {   // self-loop terms
        const unsigned hp0 = *(const unsigned*)&hb[(size_t)d0 * DIM + f0];
        const unsigned hp1 = *(const unsigned*)&hb[(size_t)d1 * DIM + f0];
        float l0 = asrc[d0 * HEADS + hd] + adst[d0 * HEADS + hd];
        l0 = (l0 > 0.f) ? l0 : SLOPE * l0;
        const float w0 = __expf(l0);
        a00 = w0 * bf2f((unsigned short)(hp0 & 0xffffu));
        a01 = w0 * bf2f((unsigned short)(hp0 >> 16));
        ds0 = w0;
        float l1 = asrc[d1 * HEADS + hd] + adst[d1 * HEADS + hd];
        l1 = (l1 > 0.f) ? l1 : SLOPE * l1;
        const float w1 = __expf(l1);
        a10 = w1 * bf2f((unsigned short)(hp1 & 0xffffu));
        a11 = w1 * bf2f((unsigned short)(hp1 >> 16));
        ds1 = w1;
    }

#define ISSUE(hreg, wreg, svv, base, j) do { \
        const int s_ = __shfl(svv, (j)); \
        hreg = *(const unsigned*)&hb[(size_t)s_ * DIM + f0]; \
        wreg = wlds[wv][((base) + (j)) * 4 + hd]; } while (0)
#define CONS(hreg, wreg, A0, A1, DS) do { \
        A0 += (wreg) * bf2f((unsigned short)((hreg) & 0xffffu)); \
        A1 += (wreg) * bf2f((unsigned short)((hreg) >> 16)); \
        DS += (wreg); } while (0)

    const int nd0 = (deg0 < 64) ? deg0 : 64;
    const int nd1 = (deg1 < 64) ? deg1 : 64;
    unsigned B0, B1, B2, B3, B4, B5, B6, B7;
    float    u0, u1, u2, u3, u4, u5, u6, u7;
    bool bfilled = false;

    int ja = 0;
    if (nd0 >= 8) {                              // node A: 8-deep pipeline
        unsigned p0, p1, p2, p3, p4, p5, p6, p7;
        float    q0, q1, q2, q3, q4, q5, q6, q7;
        ISSUE(p0, q0, sv0, 0, 0); ISSUE(p1, q1, sv0, 0, 1);
        ISSUE(p2, q2, sv0, 0, 2); ISSUE(p3, q3, sv0, 0, 3);
        ISSUE(p4, q4, sv0, 0, 4); ISSUE(p5, q5, sv0, 0, 5);
        ISSUE(p6, q6, sv0, 0, 6); ISSUE(p7, q7, sv0, 0, 7);
        for (; ja + 16 <= nd0; ja += 8) {
            CONS(p0, q0, a00, a01, ds0); ISSUE(p0, q0, sv0, 0, ja + 8);
            CONS(p1, q1, a00, a01, ds0); ISSUE(p1, q1, sv0, 0, ja + 9);
            CONS(p2, q2, a00, a01, ds0); ISSUE(p2, q2, sv0, 0, ja + 10);
            CONS(p3, q3, a00, a01, ds0); ISSUE(p3, q3, sv0, 0, ja + 11);
            CONS(p4, q4, a00, a01, ds0); ISSUE(p4, q4, sv0, 0, ja + 12);
            CONS(p5, q5, a00, a01, ds0); ISSUE(p5, q5, sv0, 0, ja + 13);
            CONS(p6, q6, a00, a01, ds0); ISSUE(p6, q6, sv0, 0, ja + 14);
            CONS(p7, q7, a00, a01, ds0); ISSUE(p7, q7, sv0, 0, ja + 15);
        }
        if (nd1 >= 8) {                          // fill B before draining A
            ISSUE(B0, u0, sv1, 64, 0); ISSUE(B1, u1, sv1, 64, 1);
            ISSUE(B2, u2, sv1, 64, 2); ISSUE(B3, u3, sv1, 64, 3);
            ISSUE(B4, u4, sv1, 64, 4); ISSUE(B5, u5, sv1, 64, 5);
            ISSUE(B6, u6, sv1, 64, 6); ISSUE(B7, u7, sv1, 64, 7);
            bfilled = true;
        }
        CONS(p0, q0, a00, a01, ds0); CONS(p1, q1, a00, a01, ds0);
        CONS(p2, q2, a00, a01, ds0); CONS(p3, q3, a00, a01, ds0);
        CONS(p4, q4, a00, a01, ds0); CONS(p5, q5, a00, a01, ds0);
        CONS(p6, q6, a00, a01, ds0); CONS(p7, q7, a00, a01, ds0);
        ja += 8;
    } else if (nd1 >= 8) {
        ISSUE(B0, u0, sv1, 64, 0); ISSUE(B1, u1, sv1, 64, 1);
        ISSUE(B2, u2, sv1, 64, 2); ISSUE(B3, u3, sv1, 64, 3);
        ISSUE(B4, u4, sv1, 64, 4); ISSUE(B5, u5, sv1, 64, 5);
        ISSUE(B6, u6, sv1, 64, 6); ISSUE(B7, u7, sv1, 64, 7);
        bfilled = true;
    }
    if (ja + 4 <= nd0) {                         // node A: 4-deep drain
        unsigned pa, pb_, pc, pd;
        float    qa, qb, qc, qd;
        ISSUE(pa, qa, sv0, 0, ja);     ISSUE(pb_, qb, sv0, 0, ja + 1);
        ISSUE(pc, qc, sv0, 0, ja + 2); ISSUE(pd, qd, sv0, 0, ja + 3);
        CONS(pa, qa, a00, a01, ds0); CONS(pb_, qb, a00, a01, ds0);
        CONS(pc, qc, a00, a01, ds0); CONS(pd, qd, a00, a01, ds0);
        ja += 4;
    }
    for (; ja < nd0; ++ja) {
        unsigned hh; float ww;
        ISSUE(hh, ww, sv0, 0, ja); CONS(hh, ww, a00, a01, ds0);
    }

    int jb = 0;
    if (bfilled) {                               // node B: steady + drain
        for (; jb + 16 <= nd1; jb += 8) {
            CONS(B0, u0, a10, a11, ds1); ISSUE(B0, u0, sv1, 64, jb + 8);
            CONS(B1, u1, a10, a11, ds1); ISSUE(B1, u1, sv1, 64, jb + 9);
            CONS(B2, u2, a10, a11, ds1); ISSUE(B2, u2, sv1, 64, jb + 10);
            CONS(B3, u3, a10, a11, ds1); ISSUE(B3, u3, sv1, 64, jb + 11);
            CONS(B4, u4, a10, a11, ds1); ISSUE(B4, u4, sv1, 64, jb + 12);
            CONS(B5, u5, a10, a11, ds1); ISSUE(B5, u5, sv1, 64, jb + 13);
            CONS(B6, u6, a10, a11, ds1); ISSUE(B6, u6, sv1, 64, jb + 14);
            CONS(B7, u7, a10, a11, ds1); ISSUE(B7, u7, sv1, 64, jb + 15);
        }
        CONS(B0, u0, a10, a11, ds1); CONS(B1, u1, a10, a11, ds1);
        CONS(B2, u2, a10, a11, ds1); CONS(B3, u3, a10, a11, ds1);
        CONS(B4, u4, a10, a11, ds1); CONS(B5, u5, a10, a11, ds1);
        CONS(B6, u6, a10, a11, ds1); CONS(B7, u7, a10, a11, ds1);
        jb += 8;
    }
    if (jb + 4 <= nd1) {
        unsigned pa, pb_, pc, pd;
        float    qa, qb, qc, qd;
        ISSUE(pa, qa, sv1, 64, jb);     ISSUE(pb_, qb, sv1, 64, jb + 1);
        ISSUE(pc, qc, sv1, 64, jb + 2); ISSUE(pd, qd, sv1, 64, jb + 3);
        CONS(pa, qa, a10, a11, ds1); CONS(pb_, qb, a10, a11, ds1);
        CONS(pc, qc, a10, a11, ds1); CONS(pd, qd, a10, a11, ds1);
        jb += 4;
    }
    for (; jb < nd1; ++jb) {
        unsigned hh; float ww;
        ISSUE(hh, ww, sv1, 64, jb); CONS(hh, ww, a10, a11, ds1);
    }
#undef ISSUE
#undef CONS
    for (int j = 64; j < deg0; ++j) {            // rare deg>64 fallback
        const int s_ = ssrc[rs0 + j];
        const unsigned hh = *(const unsigned*)&hb[(size_t)s_ * DIM + f0];
        float l_ = asrc[s_ * HEADS + hd] + adst[d0 * HEADS + hd];
        l_ = (l_ > 0.f) ? l_ : SLOPE * l_;
        const float w_ = __expf(l_);
        a00 += w_ * bf2f((unsigned short)(hh & 0xffffu));
        a01 += w_ * bf2f((unsigned short)(hh >> 16));
        ds0 += w_;
    }
    for (int j = 64; j < deg1; ++j) {
        const int s_ = ssrc[re0 + j];
        const unsigned hh = *(const unsigned*)&hb[(size_t)s_ * DIM + f0];
        float l_ = asrc[s_ * HEADS + hd] + adst[d1 * HEADS + hd];
        l_ = (l_ > 0.f) ? l_ : SLOPE * l_;
        const float w_ = __expf(l_);
        a10 += w_ * bf2f((unsigned short)(hh & 0xffffu));
        a11 += w_ * bf2f((unsigned short)(hh >> 16));
        ds1 += w_;
    }

    if (lane < 48) {
        const float i0 = 1.f / ds0, i1 = 1.f / ds1;
        const float g0 = gb[f0], g1 = gb[f0 + 1];
        *(unsigned*)&gbuf[(size_t)d0 * DIM + f0] = pack2bf(a00 * i0 + g0, a01 * i0 + g1);
        *(unsigned*)&gbuf[(size_t)d1 * DIM + f0] = pack2bf(a10 * i1 + g0, a11 * i1 + g1);
    }
}

// ---------------------------------------------------------------------------
// Kernel D (MFMA): proj = g @ PW^T + pb, + residual + LayerNorm, in-register.
// ---------------------------------------------------------------------------
__global__ __launch_bounds__(256) void k_finalize(
    const float* __restrict__ x, const unsigned short* __restrict__ pwfr,
    const float* __restrict__ pb, const float* __restrict__ lng,
    const float* __restrict__ lnb, const unsigned short* __restrict__ gbuf,
    float* __restrict__ out)
{
    const int tid = threadIdx.x, wv = tid >> 6, l = tid & 63;
    const int m = l & 15, g = l >> 4;

    bf16x8 wf[6][3];
    #pragma unroll
    for (int fb = 0; fb < 6; ++fb)
        #pragma unroll
        for (int kc = 0; kc < 3; ++kc)
            wf[fb][kc] = *(const bf16x8*)&pwfr[(size_t)((fb * 3 + kc) * 64 + l) * 8];

    float pbv[6], lgv[6], lbv[6];
    #pragma unroll
    for (int fb = 0; fb < 6; ++fb) {
        pbv[fb] = pb[fb * 16 + m];
        lgv[fb] = lng[fb * 16 + m];
        lbv[fb] = lnb[fb * 16 + m];
    }

    for (int grp = blockIdx.x * 4 + wv; grp < NGRP; grp += gridDim.x * 4) {
        const int n0 = grp * 16;
        f32x4 acc[6];
        #pragma unroll
        for (int fb = 0; fb < 6; ++fb)
            #pragma unroll
            for (int e = 0; e < 4; ++e) acc[fb][e] = 0.f;

        #pragma unroll
        for (int kc = 0; kc < 3; ++kc) {
            const bf16x8 af = *(const bf16x8*)&gbuf[(size_t)(n0 + m) * DIM + kc * 32 + g * 8];
            #pragma unroll
            for (int fb = 0; fb < 6; ++fb)
                acc[fb] = __builtin_amdgcn_mfma_f32_16x16x32_bf16(af, wf[fb][kc], acc[fb], 0, 0, 0);
        }

        float z[6][4];
        float s0 = 0.f, s1 = 0.f, s2 = 0.f, s3 = 0.f;
        float q0 = 0.f, q1 = 0.f, q2 = 0.f, q3 = 0.f;
        #pragma unroll
        for (int fb = 0; fb < 6; ++fb) {
            #pragma unroll
            for (int r = 0; r < 4; ++r) {
                const float zv = acc[fb][r] + pbv[fb] +
                    x[(size_t)(n0 + g * 4 + r) * DIM + fb * 16 + m];
                z[fb][r] = zv;
                if (r == 0) { s0 += zv; q0 += zv * zv; }
                else if (r == 1) { s1 += zv; q1 += zv * zv; }
                else if (r == 2) { s2 += zv; q2 += zv * zv; }
                else { s3 += zv; q3 += zv * zv; }
            }
        }
        #pragma unroll
        for (int mask = 1; mask < 16; mask <<= 1) {
            s0 += __shfl_xor(s0, mask); q0 += __shfl_xor(q0, mask);
            s1 += __shfl_xor(s1, mask); q1 += __shfl_xor(q1, mask);
            s2 += __shfl_xor(s2, mask); q2 += __shfl_xor(q2, mask);
            s3 += __shfl_xor(s3, mask); q3 += __shfl_xor(q3, mask);
        }
        float mu[4], iv[4];
        mu[0] = s0 * (1.f / DIM); iv[0] = rsqrtf(q0 * (1.f / DIM) - mu[0] * mu[0] + LN_EPS);
        mu[1] = s1 * (1.f / DIM); iv[1] = rsqrtf(q1 * (1.f / DIM) - mu[1] * mu[1] + LN_EPS);
        mu[2] = s2 * (1.f / DIM); iv[2] = rsqrtf(q2 * (1.f / DIM) - mu[2] * mu[2] + LN_EPS);
        mu[3] = s3 * (1.f / DIM); iv[3] = rsqrtf(q3 * (1.f / DIM) - mu[3] * mu[3] + LN_EPS);

        #pragma unroll
        for (int fb = 0; fb < 6; ++fb)
            #pragma unroll
            for (int r = 0; r < 4; ++r)
                out[(size_t)(n0 + g * 4 + r) * DIM + fb * 16 + m] =
                    lgv[fb] * (z[fb][r] - mu[r]) * iv[r] + lbv[fb];
    }
}

// ---------------------------------------------------------------------------
extern "C" void kernel_launch(void* const* d_in, const int* in_sizes, int n_in,
                              void* d_out, int out_size, void* d_ws, size_t ws_size,
                              hipStream_t stream)
{
    const float* x    = (const float*)d_in[0];
    const int*   ei   = (const int*)d_in[1];     // [2, E] int32 (harness-converted)
    const float* W    = (const float*)d_in[2];
    const float* attS = (const float*)d_in[3];
    const float* attD = (const float*)d_in[4];
    const float* gb   = (const float*)d_in[5];
    const float* PW   = (const float*)d_in[6];
    const float* pb   = (const float*)d_in[7];
    const float* lng  = (const float*)d_in[8];
    const float* lnb  = (const float*)d_in[9];
    float* out = (float*)d_out;

    char* ws = (char*)d_ws;
    unsigned* staged = (unsigned*)ws;                             // E*4 (3.2 MB)
    float* asrc    = (float*)(staged + N_EDGES);                  // N*4
    float* adst    = asrc + N_NODES * HEADS;                      // N*4
    unsigned short* hb    = (unsigned short*)(adst + N_NODES * HEADS); // N*96 bf16
    unsigned short* gbuf  = hb + (size_t)N_NODES * DIM;           // N*96 bf16
    unsigned short* wfrag = gbuf + (size_t)N_NODES * DIM;         // 18*64*8 bf16
    unsigned short* pwfrag= wfrag + 18 * 64 * 8;                  // 18*64*8 bf16
    int*   cnt     = (int*)(pwfrag + 18 * 64 * 8);                // NB2*NCH
    int*   colpre  = cnt + NB2 * NCH;                             // NB2*NCH
    int*   colsum  = colpre + NB2 * NCH;                          // NB2
    int*   offsets = colsum + NB2;                                // N+1
    int*   ssrc    = offsets + N_NODES + 1;                       // E

    k_sortA    <<<NCH, 256, 0, stream>>>(ei, cnt, W, PW, wfrag, pwfrag);
    k_sortB1   <<<NB2, 512, 0, stream>>>(cnt, colpre, colsum);
    k_sortC    <<<NCH, 256, 0, stream>>>(ei, colpre, colsum, staged);
    k_sortD    <<<NB2, 512, 0, stream>>>(staged, colsum, offsets, ssrc);
    k_transform<<<GRID_MM, 256, 0, stream>>>(x, wfrag, attS, attD, hb, asrc, adst);
    k_aggregate<<<(N_NODES / 2 * 64 + 255) / 256, 256, 0, stream>>>(offsets, ssrc, hb, asrc, adst, gb, gbuf);
    k_finalize <<<GRID_MM, 256, 0, stream>>>(x, pwfrag, pb, lng, lnb, gbuf, out);
}